// Round 1
// baseline (1891.525 us; speedup 1.0000x reference)
//
#include <hip/hip_runtime.h>
#include <stdint.h>

#define B_    16
#define D_IN_ 1024
#define T_    1024
#define K_    8192
#define D_CB_ 256
#define NTOK  (B_*T_)   // 16384

// ---- workspace layout (float offsets) ----
#define WS_WIN   0            // w_in  [256][1024]
#define WS_WOUT  262144       // w_out [1024][256]
#define WS_ENC   524288       // enc   [16384][256] (token-major z_e)
#define WS_INVE  4718592      // [16384]
#define WS_ESQ   4734976      // [16384]
#define WS_INVC  4751360      // [8192]
#define WS_CSQ   4759552      // [8192]
#define WS_KEYS  4767744      // u64 [16384] (argmin packed keys) = 32768 floats
#define WS_CNT   4800512      // [8192] counts (float)
#define WS_LOSS  4808704      // [16] per-batch sq-err sums

// ---- output layout (float offsets) ----
#define OUT_ZQ   0
#define OUT_IDX  16777216
#define OUT_COMM 16793600
#define OUT_CB   16793616
#define OUT_DIST 16793632
#define OUT_PERP 151011360
#define OUT_ACT  151011361

__device__ __forceinline__ float wave_sum(float s) {
    for (int o = 32; o; o >>= 1) s += __shfl_down(s, o, 64);
    return s;
}

// weight_norm dim=0: w[r][c] = g[r]*v[r][c]/||v[r]||  (no eps, matches ref)
__global__ void wn_kernel(const float* __restrict__ g, const float* __restrict__ v,
                          float* __restrict__ w, int rows, int cols) {
    int wave = threadIdx.x >> 6, lane = threadIdx.x & 63;
    int row = blockIdx.x * 4 + wave;
    if (row >= rows) return;
    const float* vr = v + (size_t)row * cols;
    float s = 0.f;
    for (int c = lane; c < (cols >> 2); c += 64) {
        float4 x = ((const float4*)vr)[c];
        s += x.x*x.x + x.y*x.y + x.z*x.z + x.w*x.w;
    }
    s = wave_sum(s);
    s = __shfl(s, 0, 64);
    float norm = sqrtf(s);
    float gr = g[row];
    float* wr = w + (size_t)row * cols;
    for (int c = lane; c < cols; c += 64)
        wr[c] = gr * vr[c] / norm;     // true division (match ref rounding closely)
}

// per-row (256-col) l2 stats: inv = 1/max(||x||,1e-12), sq = sum(x_n^2)
__global__ void rownorm_kernel(const float* __restrict__ x, float* __restrict__ inv,
                               float* __restrict__ sq) {
    int wave = threadIdx.x >> 6, lane = threadIdx.x & 63;
    int row = blockIdx.x * 4 + wave;
    float4 v = ((const float4*)(x + (size_t)row * D_CB_))[lane];
    float s = v.x*v.x + v.y*v.y + v.z*v.z + v.w*v.w;
    s = wave_sum(s);
    if (lane == 0) {
        float n = fmaxf(sqrtf(s), 1e-12f);
        float iv = 1.0f / n;
        inv[row] = iv;
        sq[row]  = s * iv * iv;
    }
}

// z_e GEMM: enc[b*T+t][o] = sum_i w_in[o][i]*z[b][i][t] + in_b[o]
// tile 64(o) x 64(t), KC=32, 256 thr, micro 4x4 (tx->o, ty->t)
__global__ __launch_bounds__(256) void ze_gemm(const float* __restrict__ w,
        const float* __restrict__ z, const float* __restrict__ bias,
        float* __restrict__ enc) {
    __shared__ float As[32 * 68];   // A^T [k][o]
    __shared__ float Bs[32 * 68];   // B   [k][t]
    int b  = blockIdx.z;
    int o0 = blockIdx.y * 64;
    int t0 = blockIdx.x * 64;
    int t  = threadIdx.x;
    int tx = t & 15, ty = t >> 4;
    float acc[4][4] = {};
    const float* zb = z + (size_t)b * D_IN_ * T_;
    for (int kt = 0; kt < D_IN_ / 32; ++kt) {
        #pragma unroll
        for (int p = 0; p < 2; ++p) {           // A: 64 rows x 32k, transpose-stage
            int q = p * 256 + t;
            int r = q >> 3, c4 = q & 7;
            float4 x = *(const float4*)&w[(size_t)(o0 + r) * D_IN_ + kt * 32 + c4 * 4];
            As[(c4*4+0)*68 + r] = x.x; As[(c4*4+1)*68 + r] = x.y;
            As[(c4*4+2)*68 + r] = x.z; As[(c4*4+3)*68 + r] = x.w;
        }
        #pragma unroll
        for (int p = 0; p < 2; ++p) {           // B: 32 rows(i) x 64 cols(t), natural
            int q = p * 256 + t;
            int r = q >> 4, c4 = q & 15;
            float4 x = *(const float4*)&zb[(size_t)(kt * 32 + r) * T_ + t0 + c4 * 4];
            *(float4*)&Bs[r * 68 + c4 * 4] = x;
        }
        __syncthreads();
        #pragma unroll 4
        for (int k = 0; k < 32; ++k) {
            float a[4], bv[4];
            *(float4*)a  = *(float4*)&As[k * 68 + tx * 4];
            *(float4*)bv = *(float4*)&Bs[k * 68 + ty * 4];
            #pragma unroll
            for (int i = 0; i < 4; ++i)
                #pragma unroll
                for (int j = 0; j < 4; ++j)
                    acc[i][j] = fmaf(a[j], bv[i], acc[i][j]);  // [t_sub][o_sub]
        }
        __syncthreads();
    }
    float bias4[4];
    *(float4*)bias4 = *(const float4*)&bias[o0 + tx * 4];
    #pragma unroll
    for (int i = 0; i < 4; ++i) {
        int token = b * T_ + t0 + ty * 4 + i;
        float4 v = make_float4(acc[i][0] + bias4[0], acc[i][1] + bias4[1],
                               acc[i][2] + bias4[2], acc[i][3] + bias4[3]);
        *(float4*)&enc[(size_t)token * D_CB_ + o0 + tx * 4] = v;
    }
}

// dist GEMM: dist[row][col] = esq[row] + csq[col] - 2*dot(enc_n[row], cb_n[col])
// tile 128x128, KC=32, 256 thr, micro 8x8; fused per-row argmin -> packed u64 atomicMin
#define DLD 132
__global__ __launch_bounds__(256) void dist_gemm(
        const float* __restrict__ enc, const float* __restrict__ inve,
        const float* __restrict__ esq, const float* __restrict__ cb,
        const float* __restrict__ invc, const float* __restrict__ csq,
        float* __restrict__ dist, unsigned long long* __restrict__ keys) {
    __shared__ float As[32 * DLD];
    __shared__ float Bs[32 * DLD];
    int c0 = blockIdx.x * 128;
    int r0 = blockIdx.y * 128;
    int t  = threadIdx.x;
    int tx = t & 15, ty = t >> 4;
    float acc[8][8] = {};
    for (int kt = 0; kt < D_CB_ / 32; ++kt) {
        #pragma unroll
        for (int p = 0; p < 4; ++p) {   // A: 128 tok rows x 32k, normalized, transposed
            int q = p * 256 + t;
            int r = q >> 3, c4 = q & 7;
            float iv = inve[r0 + r];
            float4 x = *(const float4*)&enc[(size_t)(r0 + r) * D_CB_ + kt * 32 + c4 * 4];
            As[(c4*4+0)*DLD + r] = x.x * iv; As[(c4*4+1)*DLD + r] = x.y * iv;
            As[(c4*4+2)*DLD + r] = x.z * iv; As[(c4*4+3)*DLD + r] = x.w * iv;
        }
        #pragma unroll
        for (int p = 0; p < 4; ++p) {   // B: 128 code rows x 32k
            int q = p * 256 + t;
            int r = q >> 3, c4 = q & 7;
            float iv = invc[c0 + r];
            float4 x = *(const float4*)&cb[(size_t)(c0 + r) * D_CB_ + kt * 32 + c4 * 4];
            Bs[(c4*4+0)*DLD + r] = x.x * iv; Bs[(c4*4+1)*DLD + r] = x.y * iv;
            Bs[(c4*4+2)*DLD + r] = x.z * iv; Bs[(c4*4+3)*DLD + r] = x.w * iv;
        }
        __syncthreads();
        #pragma unroll 4
        for (int k = 0; k < 32; ++k) {
            float a[8], bv[8];
            *(float4*)&a[0]  = *(float4*)&As[k * DLD + ty * 4];
            *(float4*)&a[4]  = *(float4*)&As[k * DLD + 64 + ty * 4];
            *(float4*)&bv[0] = *(float4*)&Bs[k * DLD + tx * 4];
            *(float4*)&bv[4] = *(float4*)&Bs[k * DLD + 64 + tx * 4];
            #pragma unroll
            for (int i = 0; i < 8; ++i)
                #pragma unroll
                for (int j = 0; j < 8; ++j)
                    acc[i][j] = fmaf(a[i], bv[j], acc[i][j]);
        }
        __syncthreads();
    }
    float s1[8], s2[8];
    #pragma unroll
    for (int i = 0; i < 4; ++i) {
        s1[i]   = esq[r0 + ty * 4 + i];      s1[4+i] = esq[r0 + 64 + ty * 4 + i];
        s2[i]   = csq[c0 + tx * 4 + i];      s2[4+i] = csq[c0 + 64 + tx * 4 + i];
    }
    unsigned long long rmin[8];
    #pragma unroll
    for (int i = 0; i < 8; ++i) rmin[i] = ~0ull;
    #pragma unroll
    for (int i = 0; i < 8; ++i) {
        int row = r0 + (i < 4 ? ty * 4 + i : 64 + ty * 4 + (i - 4));
        float d[8];
        #pragma unroll
        for (int j = 0; j < 8; ++j) {
            d[j] = fmaf(-2.0f, acc[i][j], s1[i] + s2[j]);
            int col = c0 + (j < 4 ? tx * 4 + j : 64 + tx * 4 + (j - 4));
            unsigned long long key =
                ((unsigned long long)__float_as_uint(d[j]) << 32) | (unsigned int)col;
            rmin[i] = key < rmin[i] ? key : rmin[i];
        }
        *(float4*)&dist[(size_t)row * K_ + c0 + tx * 4]      = make_float4(d[0], d[1], d[2], d[3]);
        *(float4*)&dist[(size_t)row * K_ + c0 + 64 + tx * 4] = make_float4(d[4], d[5], d[6], d[7]);
    }
    __syncthreads();
    unsigned long long* red = (unsigned long long*)As;   // 128 u64, reuse LDS
    if (t < 128) red[t] = ~0ull;
    __syncthreads();
    #pragma unroll
    for (int i = 0; i < 8; ++i) {
        int rl = (i < 4 ? ty * 4 + i : 64 + ty * 4 + (i - 4));
        atomicMin(&red[rl], rmin[i]);
    }
    __syncthreads();
    if (t < 128) atomicMin(&keys[r0 + t], red[t]);
}

// per-token: indices, (z_e - z_q)^2 partial sums, histogram
__global__ void token_kernel(const float* __restrict__ enc, const float* __restrict__ cb,
        const unsigned long long* __restrict__ keys, float* __restrict__ idx_out,
        float* __restrict__ counts, float* __restrict__ loss) {
    int wave = threadIdx.x >> 6, lane = threadIdx.x & 63;
    int tok = blockIdx.x * 4 + wave;
    int idx = (int)(unsigned int)(keys[tok] & 0xffffffffull);
    float4 e = ((const float4*)(enc + (size_t)tok * D_CB_))[lane];
    float4 q = ((const float4*)(cb  + (size_t)idx * D_CB_))[lane];
    float dx = e.x - q.x, dy = e.y - q.y, dz = e.z - q.z, dw = e.w - q.w;
    float s = dx*dx + dy*dy + dz*dz + dw*dw;
    s = wave_sum(s);
    if (lane == 0) {
        idx_out[tok] = (float)idx;
        atomicAdd(&counts[idx], 1.0f);
        atomicAdd(&loss[tok >> 10], s);
    }
}

// out GEMM: z_q_out[b][d][t] = sum_i w_out[d][i]*cb[idx[b*T+t]][i] + out_b[d]
__global__ __launch_bounds__(256) void out_gemm(const float* __restrict__ w,
        const float* __restrict__ cb, const unsigned long long* __restrict__ keys,
        const float* __restrict__ bias, float* __restrict__ out) {
    __shared__ float As[32 * 68];   // w_out^T [k][d]
    __shared__ float Bs[32 * 68];   // zq      [k][t]
    __shared__ int idxs[64];
    int b  = blockIdx.z;
    int d0 = blockIdx.y * 64;
    int t0 = blockIdx.x * 64;
    int t  = threadIdx.x;
    if (t < 64) idxs[t] = (int)(unsigned int)(keys[b * T_ + t0 + t] & 0xffffffffull);
    __syncthreads();
    int tx = t & 15, ty = t >> 4;
    float acc[4][4] = {};
    for (int kt = 0; kt < D_CB_ / 32; ++kt) {
        #pragma unroll
        for (int p = 0; p < 2; ++p) {
            int q = p * 256 + t;
            int r = q >> 3, c4 = q & 7;
            float4 x = *(const float4*)&w[(size_t)(d0 + r) * D_CB_ + kt * 32 + c4 * 4];
            As[(c4*4+0)*68 + r] = x.x; As[(c4*4+1)*68 + r] = x.y;
            As[(c4*4+2)*68 + r] = x.z; As[(c4*4+3)*68 + r] = x.w;
        }
        #pragma unroll
        for (int p = 0; p < 2; ++p) {           // gather codebook rows by token index
            int q = p * 256 + t;
            int r = q >> 3, c4 = q & 7;         // r = token_local, c4 = k-float4
            float4 x = *(const float4*)&cb[(size_t)idxs[r] * D_CB_ + kt * 32 + c4 * 4];
            Bs[(c4*4+0)*68 + r] = x.x; Bs[(c4*4+1)*68 + r] = x.y;
            Bs[(c4*4+2)*68 + r] = x.z; Bs[(c4*4+3)*68 + r] = x.w;
        }
        __syncthreads();
        #pragma unroll 4
        for (int k = 0; k < 32; ++k) {
            float a[4], bv[4];
            *(float4*)a  = *(float4*)&As[k * 68 + ty * 4];   // d dir
            *(float4*)bv = *(float4*)&Bs[k * 68 + tx * 4];   // t dir
            #pragma unroll
            for (int i = 0; i < 4; ++i)
                #pragma unroll
                for (int j = 0; j < 4; ++j)
                    acc[i][j] = fmaf(a[i], bv[j], acc[i][j]);  // [d_sub][t_sub]
        }
        __syncthreads();
    }
    #pragma unroll
    for (int i = 0; i < 4; ++i) {
        int d = d0 + ty * 4 + i;
        float bb = bias[d];
        float4 v = make_float4(acc[i][0] + bb, acc[i][1] + bb, acc[i][2] + bb, acc[i][3] + bb);
        *(float4*)&out[(size_t)b * D_IN_ * T_ + (size_t)d * T_ + t0 + tx * 4] = v;
    }
}

// scalars: perplexity, active_num, losses
__global__ void finalize_kernel(const float* __restrict__ counts, const float* __restrict__ cs,
                                const float* __restrict__ loss, float* __restrict__ out) {
    int t = threadIdx.x;
    float H = 0.f, act = 0.f;
    for (int k = t; k < K_; k += 256) {
        float c = counts[k];
        float p = c * (1.0f / 16384.0f);
        H += p * logf(p + 1e-10f);
        float ncs = cs[k] * 0.99f + c * 0.01f;
        if (ncs > 2.0f) act += 1.0f;
    }
    __shared__ float sh[8];
    for (int o = 32; o; o >>= 1) { H += __shfl_down(H, o, 64); act += __shfl_down(act, o, 64); }
    int wave = t >> 6, lane = t & 63;
    if (lane == 0) { sh[wave] = H; sh[4 + wave] = act; }
    __syncthreads();
    if (t == 0) {
        out[OUT_PERP] = expf(-(sh[0] + sh[1] + sh[2] + sh[3]));
        out[OUT_ACT]  = sh[4] + sh[5] + sh[6] + sh[7];
    }
    if (t < 16) {
        float m = loss[t] * (1.0f / 262144.0f);   // mean over D_CB*T
        out[OUT_COMM + t] = m * 0.15f;            // COMMITMENT
        out[OUT_CB + t]   = m;                    // CODEBOOK_LOSS_W = 1.0
    }
}

extern "C" void kernel_launch(void* const* d_in, const int* in_sizes, int n_in,
                              void* d_out, int out_size, void* d_ws, size_t ws_size,
                              hipStream_t stream) {
    const float* z        = (const float*)d_in[0];
    const float* in_g     = (const float*)d_in[1];
    const float* in_v     = (const float*)d_in[2];
    const float* in_b     = (const float*)d_in[3];
    const float* out_g    = (const float*)d_in[4];
    const float* out_v    = (const float*)d_in[5];
    const float* out_b    = (const float*)d_in[6];
    const float* codebook = (const float*)d_in[7];
    const float* cluster  = (const float*)d_in[8];
    float* out = (float*)d_out;
    float* ws  = (float*)d_ws;
    unsigned long long* keys = (unsigned long long*)(ws + WS_KEYS);

    hipMemsetAsync(keys, 0xFF, NTOK * sizeof(unsigned long long), stream);
    hipMemsetAsync(ws + WS_CNT, 0, (K_ + 16) * sizeof(float), stream);  // counts + loss

    wn_kernel<<<64, 256, 0, stream>>>(in_g, in_v, ws + WS_WIN, D_CB_, D_IN_);
    wn_kernel<<<256, 256, 0, stream>>>(out_g, out_v, ws + WS_WOUT, D_IN_, D_CB_);
    rownorm_kernel<<<K_ / 4, 256, 0, stream>>>(codebook, ws + WS_INVC, ws + WS_CSQ);
    ze_gemm<<<dim3(16, 4, 16), 256, 0, stream>>>(ws + WS_WIN, z, in_b, ws + WS_ENC);
    rownorm_kernel<<<NTOK / 4, 256, 0, stream>>>(ws + WS_ENC, ws + WS_INVE, ws + WS_ESQ);
    dist_gemm<<<dim3(64, 128), 256, 0, stream>>>(ws + WS_ENC, ws + WS_INVE, ws + WS_ESQ,
                                                 codebook, ws + WS_INVC, ws + WS_CSQ,
                                                 out + OUT_DIST, keys);
    token_kernel<<<NTOK / 4, 256, 0, stream>>>(ws + WS_ENC, codebook, keys,
                                               out + OUT_IDX, ws + WS_CNT, ws + WS_LOSS);
    out_gemm<<<dim3(16, 16, 16), 256, 0, stream>>>(ws + WS_WOUT, codebook, keys,
                                                   out_b, out + OUT_ZQ);
    finalize_kernel<<<1, 256, 0, stream>>>(ws + WS_CNT, cluster, ws + WS_LOSS, out);
}